// Round 4
// baseline (112.027 us; speedup 1.0000x reference)
//
#include <hip/hip_runtime.h>
#include <math.h>

#define NODES 64
#define NSTEPS 64
#define EPG 1024
#define NTHREADS 1024
#define NBLOCKS 256

typedef _Float16 f16;
typedef f16 f16x8 __attribute__((ext_vector_type(8)));
typedef f16 f16x4 __attribute__((ext_vector_type(4)));
typedef float f32x4 __attribute__((ext_vector_type(4)));

// ---- LDS layout (byte offsets). f16 [64][72] = 9216 B ----
#define OFF_Y1    0        // setup: M1 row-major   scan: Y1
#define OFF_Y2    9216     // setup: M2 row-major   scan: Y2
#define OFF_Y3    18432    // setup: M3 row-major   scan: Y3
#define OFF_HA    27648    // setup: M1^T           scan: h buf A (row-major)
#define OFF_HB    36864    // setup: M2^T           scan: h buf B
#define OFF_TT    46080    // setup: X^T [t][n]     scan: h^T [feat][node]
#define OFF_ZT    55296    // 32768 B: setup first = f32 Lap scratch (16K); then f16 Z [64 t][64 n][4 k]
#define OFF_WT    88064    // 38912 B: f16 Wcat^T [64 c][304 K]; phase3: sT1g/sT2g
#define OFF_DEG   126976
#define OFF_DINV  127232
#define OFF_BSUM  127488
#define OFF_LOGIT 127744
#define SMEM_BYTES 127872

__device__ __forceinline__ f32x4 mfma16(f16x8 a, f16x8 b, f32x4 c) {
  return __builtin_amdgcn_mfma_f32_16x16x32_f16(a, b, c, 0, 0, 0);
}

// single 16x16 tile, K=64: D[i][j] = sum_m A[rb*16+i][m] * B[cb*16+j][m], strides 72
__device__ __forceinline__ f32x4 mm64t(const f16* __restrict__ A, const f16* __restrict__ B,
                                       int rb, int cb, int lrow, int lk)
{
  f32x4 d = (f32x4){0.f, 0.f, 0.f, 0.f};
#pragma unroll
  for (int ch = 0; ch < 2; ++ch) {
    const f16x8 a = *(const f16x8*)(A + (rb * 16 + lrow) * 72 + ch * 32 + lk * 8);
    const f16x8 b = *(const f16x8*)(B + (cb * 16 + lrow) * 72 + ch * 32 + lk * 8);
    d = mfma16(a, b, d);
  }
  return d;
}

// fp32 4x4-tile matmul (phase 3)
template<int K>
__device__ __forceinline__ void mm4x4_acc(float acc[4][4],
                                          const float* __restrict__ A, int lda, int arow,
                                          const float* __restrict__ Bm, int ldb, int j4)
{
#pragma unroll 2
  for (int kc = 0; kc < K; kc += 4) {
    float av[4][4];
    float bv[4][4];
#pragma unroll
    for (int rr = 0; rr < 4; ++rr) {
      const float4 t = *(const float4*)(A + (arow + rr) * lda + kc);
      av[rr][0] = t.x; av[rr][1] = t.y; av[rr][2] = t.z; av[rr][3] = t.w;
    }
#pragma unroll
    for (int kk = 0; kk < 4; ++kk) {
      const float4 t = *(const float4*)(Bm + (kc + kk) * ldb + j4);
      bv[kk][0] = t.x; bv[kk][1] = t.y; bv[kk][2] = t.z; bv[kk][3] = t.w;
    }
#pragma unroll
    for (int rr = 0; rr < 4; ++rr)
#pragma unroll
      for (int cc = 0; cc < 4; ++cc) {
        float s = acc[rr][cc];
#pragma unroll
        for (int kk = 0; kk < 4; ++kk) s += av[rr][kk] * bv[kk][cc];
        acc[rr][cc] = s;
      }
  }
}

__global__ __launch_bounds__(NTHREADS)
void gcrnn_mfma3(const float* __restrict__ x,     // [16384][64]
                 const float* __restrict__ ew,    // [262144]
                 const float* __restrict__ wA,    // [4][1][64]
                 const float* __restrict__ bA,    // [64]
                 const float* __restrict__ wB,    // [4][64][64]
                 const float* __restrict__ bB,    // [64]
                 const float* __restrict__ w1,    // [64][64]
                 const float* __restrict__ b1,    // [64]
                 const float* __restrict__ w2,    // [64][32]
                 const float* __restrict__ b2,    // [32]
                 const float* __restrict__ wfc,   // [2048][4]
                 const float* __restrict__ bfc,   // [4]
                 const int* __restrict__ esrc,
                 const int* __restrict__ edst,
                 float* __restrict__ out)         // [256][4]
{
  __shared__ __align__(16) char smem[SMEM_BYTES];

  f16*   sM1   = (f16*)(smem + OFF_Y1);
  f16*   sM2   = (f16*)(smem + OFF_Y2);
  f16*   sM3   = (f16*)(smem + OFF_Y3);
  f16*   sHA   = (f16*)(smem + OFF_HA);   // M1T during setup
  f16*   sHB   = (f16*)(smem + OFF_HB);   // M2T during setup
  f16*   sTt   = (f16*)(smem + OFF_TT);   // X^T during setup, h^T in scan
  f16*   sZt   = (f16*)(smem + OFF_ZT);   // [t][n][4]
  float* sLgF  = (float*)(smem + OFF_ZT); // fp32 Lap scratch (dead before sZt writes)
  f16*   sWt   = (f16*)(smem + OFF_WT);
  float* sDeg  = (float*)(smem + OFF_DEG);
  float* sDinv = (float*)(smem + OFF_DINV);
  float* sBsum = (float*)(smem + OFF_BSUM);
  float* sLogit= (float*)(smem + OFF_LOGIT);

  const int b = blockIdx.x, tid = threadIdx.x;
  const int gbase = b * NODES, ebase = b * EPG;
  const int wid = tid >> 6, lane = tid & 63;
  const int lrow = lane & 15, lk = lane >> 4;

  // setup tile assignment (16 waves, 1 tile each: 4x4 grid)
  const int rbS = wid >> 2, cbS = wid & 3;
  // scan phase A: tiles tau = 3*wid..3*wid+2, tau = fb*12 + k*4 + nb
  const int fbA = wid >> 2;
  // scan phase B: output tile (cbB, nbB)
  const int cbB = wid >> 2, nbB = wid & 3;

  // ---------------- W0: stage + zero ----------------
  for (int idx = tid; idx < 4096; idx += NTHREADS) sLgF[idx] = 0.f;
  if (tid < 64) { sDeg[tid] = 0.f; sBsum[tid] = bA[tid] + bB[tid]; }
  // Wt [c][K=304]: 0..255 = wB (K=64k+j), 256..259 = wA, 260..303 = 0
  for (int idx = tid; idx < 64 * 260; idx += NTHREADS) {
    const int k = idx >> 6, c = idx & 63;
    const float v = (k < 256) ? wB[(k >> 6) * 4096 + (k & 63) * 64 + c]
                              : wA[(k - 256) * 64 + c];
    sWt[c * 304 + k] = (f16)v;
  }
  for (int idx = tid; idx < 64 * 44; idx += NTHREADS) {
    const int c = idx / 44, j = idx - c * 44;
    sWt[c * 304 + 260 + j] = (f16)0.f;
  }
  // X^T into sTt: sTt[t*72+n] = x[gbase+n][t]
  for (int idx = tid; idx < 4096; idx += NTHREADS) {
    const int n = idx >> 6, t = idx & 63;
    sTt[t * 72 + n] = (f16)x[gbase * 64 + idx];
  }
  __syncthreads();

  // ---------------- Laplacian build ----------------
  for (int e = tid; e < EPG; e += NTHREADS)
    atomicAdd(&sDeg[esrc[ebase + e] - gbase], ew[ebase + e]);
  __syncthreads();
  if (tid < 64) { const float d = sDeg[tid]; sDinv[tid] = (d > 0.f) ? rsqrtf(d) : 0.f; }
  __syncthreads();
  for (int e = tid; e < EPG; e += NTHREADS) {
    const int sl = esrc[ebase + e] - gbase, dl = edst[ebase + e] - gbase;
    atomicAdd(&sLgF[dl * 64 + sl], -(sDinv[sl] * ew[ebase + e] * sDinv[dl]));
  }
  __syncthreads();
  // stage fp16 Lambda row-major (sM1) + transposed (sHA)
  for (int idx = tid; idx < 4096; idx += NTHREADS) {
    const int i = idx >> 6, j = idx & 63;
    const f16 v = (f16)sLgF[idx];
    sM1[i * 72 + j] = v;
    sHA[j * 72 + i] = v;
  }
  __syncthreads();

  // ---------------- W5: M2 (both layouts) + Z1 + Z slot0 ----------------
  {
    f32x4 d;
    d = mm64t(sHA, sM1, rbS, cbS, lrow, lk);          // D[i][j] = Lam^2[j][i]
    {
      const int p0 = rbS * 16 + lk * 4, q = cbS * 16 + lrow;
      f16x4 w;
#pragma unroll
      for (int r = 0; r < 4; ++r) w[r] = (f16)(2.f * d[r] - ((p0 + r) == q ? 1.f : 0.f));
      *(f16x4*)(sM2 + q * 72 + p0) = w;               // M2 row-major
    }
    d = mm64t(sM1, sHA, rbS, cbS, lrow, lk);          // D[i][j] = Lam^2[i][j]
    {
      const int p0 = rbS * 16 + lk * 4, q = cbS * 16 + lrow;
      f16x4 w;
#pragma unroll
      for (int r = 0; r < 4; ++r) w[r] = (f16)(2.f * d[r] - ((p0 + r) == q ? 1.f : 0.f));
      *(f16x4*)(sHB + q * 72 + p0) = w;               // M2^T
    }
    d = mm64t(sM1, sTt, rbS, cbS, lrow, lk);          // Z1[n=i][t=j]
    {
      const int p0 = rbS * 16 + lk * 4, q = cbS * 16 + lrow;
#pragma unroll
      for (int r = 0; r < 4; ++r) sZt[q * 256 + (p0 + r) * 4 + 1] = (f16)d[r];
    }
    // Z slot 0 = x (LGF dead now)
    for (int idx = tid; idx < 4096; idx += NTHREADS) {
      const int t = idx >> 6, n = idx & 63;
      sZt[t * 256 + n * 4 + 0] = sTt[t * 72 + n];
    }
  }
  __syncthreads();

  // ---------------- W6: M3 + Z2 ----------------
  {
    f32x4 d;
    d = mm64t(sHB, sM1, rbS, cbS, lrow, lk);          // D[i][j] = (Lam M2)[j][i]
    {
      const int p0 = rbS * 16 + lk * 4, q = cbS * 16 + lrow;
      const f16x4 lv = *(const f16x4*)(sM1 + q * 72 + p0);
      f16x4 w;
#pragma unroll
      for (int r = 0; r < 4; ++r) w[r] = (f16)(2.f * d[r] - (float)lv[r]);
      *(f16x4*)(sM3 + q * 72 + p0) = w;               // M3 row-major
    }
    d = mm64t(sM2, sTt, rbS, cbS, lrow, lk);          // Z2[n][t]
    {
      const int p0 = rbS * 16 + lk * 4, q = cbS * 16 + lrow;
#pragma unroll
      for (int r = 0; r < 4; ++r) sZt[q * 256 + (p0 + r) * 4 + 2] = (f16)d[r];
    }
  }
  __syncthreads();

  // ---------------- W7: Z3 ----------------
  {
    f32x4 d = mm64t(sM3, sTt, rbS, cbS, lrow, lk);    // Z3[n][t]
    const int p0 = rbS * 16 + lk * 4, q = cbS * 16 + lrow;
#pragma unroll
    for (int r = 0; r < 4; ++r) sZt[q * 256 + (p0 + r) * 4 + 3] = (f16)d[r];
  }
  __syncthreads();

  // ---------------- W8: preload frags, zero h buffers ----------------
  f16x8 mfrag[3][2];
  int   mnb[3];
  f16*  mYb[3];
  f16x8 wfrag[9];
  f32x4 bsr;
  {
#pragma unroll
    for (int i = 0; i < 3; ++i) {
      const int tau = 3 * wid + i;
      const int k = (tau % 12) >> 2;
      const int nb = tau & 3;
      mnb[i] = nb;
      mYb[i] = (f16*)smem + k * 4608;                 // Y1/Y2/Y3 base (f16 units)
#pragma unroll
      for (int ch = 0; ch < 2; ++ch)
        mfrag[i][ch] = *(const f16x8*)(mYb[i] + (nb * 16 + lrow) * 72 + ch * 32 + lk * 8);
    }
#pragma unroll
    for (int ch = 0; ch < 9; ++ch)
      wfrag[ch] = *(const f16x8*)(sWt + (cbB * 16 + lrow) * 304 + ch * 32 + lk * 8);
#pragma unroll
    for (int r = 0; r < 4; ++r) bsr[r] = sBsum[cbB * 16 + lk * 4 + r];
    // zero hA, hB, sTt
    for (int idx = tid; idx < 3 * 2304; idx += NTHREADS)
      ((int*)(smem + OFF_HA))[idx] = 0;
  }
  __syncthreads();

  // ---------------- scan: 64 steps, 2 barriers each ----------------
  const int bn = nbB * 16 + lrow;

  auto step = [&](int t, const f16* __restrict__ hrCur, f16* __restrict__ hrNxt) {
    // ---- Phase A: Y_k^ tiles (wave owns 3 tiles, shared A-frag) ----
    {
      const f16x8 a0 = *(const f16x8*)(sTt + (fbA * 16 + lrow) * 72 + lk * 8);
      const f16x8 a1 = *(const f16x8*)(sTt + (fbA * 16 + lrow) * 72 + 32 + lk * 8);
      f32x4 y0 = (f32x4){0.f,0.f,0.f,0.f}, y1 = y0, y2 = y0;
      y0 = mfma16(a0, mfrag[0][0], y0);
      y1 = mfma16(a0, mfrag[1][0], y1);
      y2 = mfma16(a0, mfrag[2][0], y2);
      y0 = mfma16(a1, mfrag[0][1], y0);
      y1 = mfma16(a1, mfrag[1][1], y1);
      y2 = mfma16(a1, mfrag[2][1], y2);
      f32x4 yy[3] = {y0, y1, y2};
#pragma unroll
      for (int i = 0; i < 3; ++i) {
        f16x4 w;
#pragma unroll
        for (int r = 0; r < 4; ++r) w[r] = (f16)yy[i][r];
        *(f16x4*)(mYb[i] + (mnb[i] * 16 + lrow) * 72 + fbA * 16 + lk * 4) = w;
      }
    }
    __syncthreads();
    // ---- Phase B: h' = sigmoid([h|Y1|Y2|Y3|z] @ Wcat + b), dual chains ----
    {
      f32x4 pa = bsr;
      f32x4 pb = (f32x4){0.f, 0.f, 0.f, 0.f};
      f16x8 bb;
      bb = *(const f16x8*)(hrCur + bn * 72 + lk * 8);       pa = mfma16(wfrag[0], bb, pa);
      bb = *(const f16x8*)(hrCur + bn * 72 + 32 + lk * 8);  pb = mfma16(wfrag[1], bb, pb);
      bb = *(const f16x8*)(sM1 + bn * 72 + lk * 8);         pa = mfma16(wfrag[2], bb, pa);
      bb = *(const f16x8*)(sM1 + bn * 72 + 32 + lk * 8);    pb = mfma16(wfrag[3], bb, pb);
      bb = *(const f16x8*)(sM2 + bn * 72 + lk * 8);         pa = mfma16(wfrag[4], bb, pa);
      bb = *(const f16x8*)(sM2 + bn * 72 + 32 + lk * 8);    pb = mfma16(wfrag[5], bb, pb);
      bb = *(const f16x8*)(sM3 + bn * 72 + lk * 8);         pa = mfma16(wfrag[6], bb, pa);
      bb = *(const f16x8*)(sM3 + bn * 72 + 32 + lk * 8);    pb = mfma16(wfrag[7], bb, pb);
      {
        const f16x4 zv = *(const f16x4*)(sZt + t * 256 + bn * 4);
        f16x8 zb;
        zb[0] = zv[0]; zb[1] = zv[1]; zb[2] = zv[2]; zb[3] = zv[3];
        zb[4] = (f16)0.f; zb[5] = (f16)0.f; zb[6] = (f16)0.f; zb[7] = (f16)0.f;
        pa = mfma16(wfrag[8], zb, pa);
      }
      const f32x4 p = pa + pb;
      f16x4 hv;
      float hf[4];
#pragma unroll
      for (int r = 0; r < 4; ++r) {
        hf[r] = 1.f / (1.f + __expf(-p[r]));
        hv[r] = (f16)hf[r];
      }
      *(f16x4*)(hrNxt + bn * 72 + cbB * 16 + lk * 4) = hv;   // row-major h'
#pragma unroll
      for (int r = 0; r < 4; ++r)                             // h'^T scatter
        sTt[(cbB * 16 + lk * 4 + r) * 72 + bn] = hv[r];
    }
    __syncthreads();
  };

#pragma unroll 1
  for (int tt = 0; tt < NSTEPS / 2; ++tt) {
    step(2 * tt, sHA, sHB);
    step(2 * tt + 1, sHB, sHA);
  }
  // final h (fp16, row-major) in sHA

  // ---------------- Phase 3: GCN x2 + FC + log_softmax (fp32) ----------------
  float* sLgG = (float*)(smem + OFF_ZT);              // [64][68]
  float* sT1g = (float*)(smem + OFF_WT);              // [64][68]
  float* sT2g = (float*)(smem + OFF_WT + 17408);      // [64][68]

  for (int idx = tid; idx < 64 * 68; idx += NTHREADS) sLgG[idx] = 0.f;
  if (tid < 64) sDeg[tid] = 0.f;
  for (int idx = tid; idx < 4096; idx += NTHREADS) {
    const int n = idx >> 6, c = idx & 63;
    sT1g[n * 68 + c] = (float)sHA[n * 72 + c];
  }
  if (tid < 4) sLogit[tid] = bfc[tid];
  __syncthreads();
  for (int e = tid; e < EPG; e += NTHREADS)
    atomicAdd(&sDeg[edst[ebase + e] - gbase], ew[ebase + e]);
  __syncthreads();
  if (tid < 64) sDinv[tid] = rsqrtf(sDeg[tid] + 1.f);
  __syncthreads();
  for (int e = tid; e < EPG; e += NTHREADS) {
    const int sl = esrc[ebase + e] - gbase, dl = edst[ebase + e] - gbase;
    atomicAdd(&sLgG[dl * 68 + sl], sDinv[sl] * ew[ebase + e] * sDinv[dl]);
  }
  __syncthreads();
  if (tid < 64) sLgG[tid * 68 + tid] += sDinv[tid] * sDinv[tid];
  __syncthreads();

  const bool isTile = tid < 256;
  const int i4 = ((tid >> 4) & 15) * 4;
  const int j4 = (tid & 15) * 4;

  if (isTile) {                                       // xw1 = h @ w1 -> sT2g
    float m[4][4] = {};
    mm4x4_acc<64>(m, sT1g, 68, i4, w1, 64, j4);
#pragma unroll
    for (int rr = 0; rr < 4; ++rr)
      *(float4*)(sT2g + (i4 + rr) * 68 + j4) = make_float4(m[rr][0], m[rr][1], m[rr][2], m[rr][3]);
  }
  __syncthreads();
  if (isTile) {                                       // z1 = relu(Ag @ xw1 + b1) -> sT1g
    float m[4][4] = {};
    mm4x4_acc<64>(m, sLgG, 68, i4, sT2g, 68, j4);
#pragma unroll
    for (int rr = 0; rr < 4; ++rr) {
      float4 o;
      o.x = fmaxf(m[rr][0] + b1[j4 + 0], 0.f);
      o.y = fmaxf(m[rr][1] + b1[j4 + 1], 0.f);
      o.z = fmaxf(m[rr][2] + b1[j4 + 2], 0.f);
      o.w = fmaxf(m[rr][3] + b1[j4 + 3], 0.f);
      *(float4*)(sT1g + (i4 + rr) * 68 + j4) = o;
    }
  }
  __syncthreads();
  if (isTile && j4 < 32) {                            // xw2 = z1 @ w2 -> sT2g
    float m[4][4] = {};
    mm4x4_acc<64>(m, sT1g, 68, i4, w2, 32, j4);
#pragma unroll
    for (int rr = 0; rr < 4; ++rr)
      *(float4*)(sT2g + (i4 + rr) * 68 + j4) = make_float4(m[rr][0], m[rr][1], m[rr][2], m[rr][3]);
  }
  __syncthreads();
  if (isTile && j4 < 32) {                            // z2 = relu(Ag @ xw2 + b2) -> sT1g
    float m[4][4] = {};
    mm4x4_acc<64>(m, sLgG, 68, i4, sT2g, 68, j4);
#pragma unroll
    for (int rr = 0; rr < 4; ++rr) {
      float4 o;
      o.x = fmaxf(m[rr][0] + b2[j4 + 0], 0.f);
      o.y = fmaxf(m[rr][1] + b2[j4 + 1], 0.f);
      o.z = fmaxf(m[rr][2] + b2[j4 + 2], 0.f);
      o.w = fmaxf(m[rr][3] + b2[j4 + 3], 0.f);
      *(float4*)(sT1g + (i4 + rr) * 68 + j4) = o;
    }
  }
  __syncthreads();

  // FC + log_softmax
  float p0 = 0.f, p1 = 0.f, p2 = 0.f, p3 = 0.f;
  for (int f = tid; f < 2048; f += NTHREADS) {
    const int n = f >> 5, c = f & 31;
    const float v = sT1g[n * 68 + c];
    const float4 wv = *(const float4*)(wfc + f * 4);
    p0 += v * wv.x; p1 += v * wv.y; p2 += v * wv.z; p3 += v * wv.w;
  }
#pragma unroll
  for (int off = 1; off < 64; off <<= 1) {
    p0 += __shfl_xor(p0, off);
    p1 += __shfl_xor(p1, off);
    p2 += __shfl_xor(p2, off);
    p3 += __shfl_xor(p3, off);
  }
  if ((tid & 63) == 0) {
    atomicAdd(&sLogit[0], p0);
    atomicAdd(&sLogit[1], p1);
    atomicAdd(&sLogit[2], p2);
    atomicAdd(&sLogit[3], p3);
  }
  __syncthreads();
  if (tid == 0) {
    const float l0 = sLogit[0], l1 = sLogit[1], l2 = sLogit[2], l3 = sLogit[3];
    const float mx = fmaxf(fmaxf(l0, l1), fmaxf(l2, l3));
    const float s = expf(l0 - mx) + expf(l1 - mx) + expf(l2 - mx) + expf(l3 - mx);
    const float lse = mx + logf(s);
    out[b * 4 + 0] = l0 - lse;
    out[b * 4 + 1] = l1 - lse;
    out[b * 4 + 2] = l2 - lse;
    out[b * 4 + 3] = l3 - lse;
  }
}

extern "C" void kernel_launch(void* const* d_in, const int* in_sizes, int n_in,
                              void* d_out, int out_size, void* d_ws, size_t ws_size,
                              hipStream_t stream) {
  gcrnn_mfma3<<<NBLOCKS, NTHREADS, 0, stream>>>(
      (const float*)d_in[0],   // x
      (const float*)d_in[1],   // edge_weight
      (const float*)d_in[2],   // wA
      (const float*)d_in[3],   // bA
      (const float*)d_in[4],   // wB
      (const float*)d_in[5],   // bB
      (const float*)d_in[6],   // w1
      (const float*)d_in[7],   // b1
      (const float*)d_in[8],   // w2
      (const float*)d_in[9],   // b2
      (const float*)d_in[10],  // wfc
      (const float*)d_in[11],  // bfc
      (const int*)d_in[12],    // edge_src
      (const int*)d_in[13],    // edge_dst
      (float*)d_out);
}

// Round 6
// 111.815 us; speedup vs baseline: 1.0019x; 1.0019x over previous
//
#include <hip/hip_runtime.h>
#include <math.h>

#define NODES 64
#define NSTEPS 64
#define EPG 1024
#define NTHREADS 512
#define NBLOCKS 256

typedef _Float16 f16;
typedef f16 f16x8 __attribute__((ext_vector_type(8)));
typedef f16 f16x4 __attribute__((ext_vector_type(4)));
typedef float f32x4 __attribute__((ext_vector_type(4)));

// ---- LDS byte offsets ----
// setup names                          scan/phase3 reuse
#define OFF_M1    0        // Lambda row-major [64][72] f16     -> scan: Yfrag [3 k][4 nb][2 ch][64 lane][16B] = 24576
#define OFF_YF    0
#define OFF_M2    9216
#define OFF_M3    18432
#define OFF_M1T   27648    // Lambda^T [64][72]                 -> scan: hfrag  [4 nb][2 ch][64][16B] = 8192
#define OFF_HF    27648
#define OFF_M2T   36864    // M2^T [64][72]                     -> scan: hTfrag [4 fb][2 ch][64][16B] = 8192
#define OFF_HTF   36864
#define OFF_XT    46080    // X^T [64][72] f16 (setup only)
#define OFF_ZT    55296    // f16 [64 t][64 n][4 k] = 32768     -> phase3: sLgG f32 [64][68]
#define OFF_WT    88064    // f16 [64 c][304 K] = 38912         -> phase3: sT1g + sT2g f32 [64][68]
#define OFF_LGF   126976   // f32 [64][64] Laplacian scratch
#define OFF_DEG   143360
#define OFF_DINV  143616
#define OFF_BSUM  143872
#define OFF_LOGIT 144128
#define SMEM_BYTES 144384

__device__ __forceinline__ f32x4 mfma16(f16x8 a, f16x8 b, f32x4 c) {
  return __builtin_amdgcn_mfma_f32_16x16x32_f16(a, b, c, 0, 0, 0);
}

#if __has_builtin(__builtin_amdgcn_mfma_f32_16x16x16f16)
#define HAVE_MFMA_K16 1
__device__ __forceinline__ f32x4 mfma16k16(f16x4 a, f16x4 b, f32x4 c) {
  return __builtin_amdgcn_mfma_f32_16x16x16f16(a, b, c, 0, 0, 0);
}
#else
#define HAVE_MFMA_K16 0
#endif

// setup: D[i][j] = sum_m A[rb*16+i][m] * B[cb*16+j][m], strides 72
__device__ __forceinline__ f32x4 mm64t(const f16* __restrict__ A, const f16* __restrict__ B,
                                       int rb, int cb, int lrow, int lk)
{
  f32x4 d = (f32x4){0.f, 0.f, 0.f, 0.f};
#pragma unroll
  for (int ch = 0; ch < 2; ++ch) {
    const f16x8 a = *(const f16x8*)(A + (rb * 16 + lrow) * 72 + ch * 32 + lk * 8);
    const f16x8 b = *(const f16x8*)(B + (cb * 16 + lrow) * 72 + ch * 32 + lk * 8);
    d = mfma16(a, b, d);
  }
  return d;
}

// fp32 4x4-tile matmul (phase 3)
template<int K>
__device__ __forceinline__ void mm4x4_acc(float acc[4][4],
                                          const float* __restrict__ A, int lda, int arow,
                                          const float* __restrict__ Bm, int ldb, int j4)
{
#pragma unroll 2
  for (int kc = 0; kc < K; kc += 4) {
    float av[4][4];
    float bv[4][4];
#pragma unroll
    for (int rr = 0; rr < 4; ++rr) {
      const float4 t = *(const float4*)(A + (arow + rr) * lda + kc);
      av[rr][0] = t.x; av[rr][1] = t.y; av[rr][2] = t.z; av[rr][3] = t.w;
    }
#pragma unroll
    for (int kk = 0; kk < 4; ++kk) {
      const float4 t = *(const float4*)(Bm + (kc + kk) * ldb + j4);
      bv[kk][0] = t.x; bv[kk][1] = t.y; bv[kk][2] = t.z; bv[kk][3] = t.w;
    }
#pragma unroll
    for (int rr = 0; rr < 4; ++rr)
#pragma unroll
      for (int cc = 0; cc < 4; ++cc) {
        float s = acc[rr][cc];
#pragma unroll
        for (int kk = 0; kk < 4; ++kk) s += av[rr][kk] * bv[kk][cc];
        acc[rr][cc] = s;
      }
  }
}

__global__ __launch_bounds__(NTHREADS, 2)
void gcrnn_mfma4(const float* __restrict__ x,     // [16384][64]
                 const float* __restrict__ ew,    // [262144]
                 const float* __restrict__ wA,    // [4][1][64]
                 const float* __restrict__ bA,    // [64]
                 const float* __restrict__ wB,    // [4][64][64]
                 const float* __restrict__ bB,    // [64]
                 const float* __restrict__ w1,    // [64][64]
                 const float* __restrict__ b1,    // [64]
                 const float* __restrict__ w2,    // [64][32]
                 const float* __restrict__ b2,    // [32]
                 const float* __restrict__ wfc,   // [2048][4]
                 const float* __restrict__ bfc,   // [4]
                 const int* __restrict__ esrc,
                 const int* __restrict__ edst,
                 float* __restrict__ out)         // [256][4]
{
  __shared__ __align__(16) char smem[SMEM_BYTES];

  f16*   sM1   = (f16*)(smem + OFF_M1);
  f16*   sM2   = (f16*)(smem + OFF_M2);
  f16*   sM3   = (f16*)(smem + OFF_M3);
  f16*   sM1T  = (f16*)(smem + OFF_M1T);
  f16*   sM2T  = (f16*)(smem + OFF_M2T);
  f16*   sXT   = (f16*)(smem + OFF_XT);
  f16*   sZt   = (f16*)(smem + OFF_ZT);
  f16*   sWt   = (f16*)(smem + OFF_WT);
  float* sLgF  = (float*)(smem + OFF_LGF);
  float* sDeg  = (float*)(smem + OFF_DEG);
  float* sDinv = (float*)(smem + OFF_DINV);
  float* sBsum = (float*)(smem + OFF_BSUM);
  float* sLogit= (float*)(smem + OFF_LOGIT);

  const int b = blockIdx.x, tid = threadIdx.x;
  const int gbase = b * NODES, ebase = b * EPG;
  const int wid = tid >> 6, lane = tid & 63;
  const int lrow = lane & 15, lk = lane >> 4;
  const bool isA = wid < 4;
  const int fb = wid;          // A-wave role (0..3)
  const int nb = wid & 3;      // B-wave role

  // ---------------- W0: stage + zero ----------------
  for (int idx = tid; idx < 4096; idx += NTHREADS) sLgF[idx] = 0.f;
  if (tid < 64) { sDeg[tid] = 0.f; sBsum[tid] = bA[tid] + bB[tid]; }
  // Wt [c][K=304]: 0..255 = wB (K=64k+j), 256..259 = wA, 260..303 = 0
  for (int idx = tid; idx < 64 * 260; idx += NTHREADS) {
    const int k = idx >> 6, c = idx & 63;
    const float v = (k < 256) ? wB[(k >> 6) * 4096 + (k & 63) * 64 + c]
                              : wA[(k - 256) * 64 + c];
    sWt[c * 304 + k] = (f16)v;
  }
  for (int idx = tid; idx < 64 * 44; idx += NTHREADS) {
    const int c = idx / 44, j = idx - c * 44;
    sWt[c * 304 + 260 + j] = (f16)0.f;
  }
  // X^T: sXT[t*72+n] = x[gbase+n][t]  (coalesced global read)
  for (int idx = tid; idx < 4096; idx += NTHREADS) {
    const int n = idx >> 6, t = idx & 63;
    sXT[t * 72 + n] = (f16)x[gbase * 64 + idx];
  }
  __syncthreads();

  // ---------------- Laplacian build ----------------
  for (int e = tid; e < EPG; e += NTHREADS)
    atomicAdd(&sDeg[esrc[ebase + e] - gbase], ew[ebase + e]);
  __syncthreads();
  if (tid < 64) { const float d = sDeg[tid]; sDinv[tid] = (d > 0.f) ? rsqrtf(d) : 0.f; }
  __syncthreads();
  for (int e = tid; e < EPG; e += NTHREADS) {
    const int sl = esrc[ebase + e] - gbase, dl = edst[ebase + e] - gbase;
    atomicAdd(&sLgF[dl * 64 + sl], -(sDinv[sl] * ew[ebase + e] * sDinv[dl]));
  }
  __syncthreads();
  for (int idx = tid; idx < 4096; idx += NTHREADS) {
    const int i = idx >> 6, j = idx & 63;
    const f16 v = (f16)sLgF[idx];
    sM1[i * 72 + j] = v;
    sM1T[j * 72 + i] = v;
  }
  __syncthreads();

  const int rbS = wid >> 1;   // setup: 8 waves x 2 tiles

  // ---------------- W5: M2 (both layouts) + Z1 + Zslot0 ----------------
#pragma unroll
  for (int s = 0; s < 2; ++s) {
    const int cbS = (wid & 1) * 2 + s;
    f32x4 d;
    d = mm64t(sM1T, sM1, rbS, cbS, lrow, lk);     // D[p][q] = Lam^2[q][p]
    {
      const int p0 = rbS * 16 + lk * 4, q = cbS * 16 + lrow;
      f16x4 w;
#pragma unroll
      for (int r = 0; r < 4; ++r) w[r] = (f16)(2.f * d[r] - ((p0 + r) == q ? 1.f : 0.f));
      *(f16x4*)(sM2 + q * 72 + p0) = w;           // M2 row-major
    }
    d = mm64t(sM1, sM1T, rbS, cbS, lrow, lk);     // D[p][q] = Lam^2[p][q]
    {
      const int p0 = rbS * 16 + lk * 4, q = cbS * 16 + lrow;
      f16x4 w;
#pragma unroll
      for (int r = 0; r < 4; ++r) w[r] = (f16)(2.f * d[r] - ((p0 + r) == q ? 1.f : 0.f));
      *(f16x4*)(sM2T + q * 72 + p0) = w;          // M2^T
    }
    d = mm64t(sM1, sXT, rbS, cbS, lrow, lk);      // Z1[n=p][t=q]
    {
      const int p0 = rbS * 16 + lk * 4, q = cbS * 16 + lrow;
#pragma unroll
      for (int r = 0; r < 4; ++r) sZt[q * 256 + (p0 + r) * 4 + 1] = (f16)d[r];
    }
  }
  for (int idx = tid; idx < 4096; idx += NTHREADS) {
    const int t = idx >> 6, n = idx & 63;
    sZt[t * 256 + n * 4 + 0] = sXT[t * 72 + n];
  }
  __syncthreads();

  // ---------------- W6: M3 + Z2 ----------------
#pragma unroll
  for (int s = 0; s < 2; ++s) {
    const int cbS = (wid & 1) * 2 + s;
    f32x4 d;
    d = mm64t(sM2T, sM1, rbS, cbS, lrow, lk);     // D[p][q] = (Lam M2)[q][p]
    {
      const int p0 = rbS * 16 + lk * 4, q = cbS * 16 + lrow;
      const f16x4 lv = *(const f16x4*)(sM1 + q * 72 + p0);
      f16x4 w;
#pragma unroll
      for (int r = 0; r < 4; ++r) w[r] = (f16)(2.f * d[r] - (float)lv[r]);
      *(f16x4*)(sM3 + q * 72 + p0) = w;           // M3 row-major
    }
    d = mm64t(sM2, sXT, rbS, cbS, lrow, lk);      // Z2[n][t]
    {
      const int p0 = rbS * 16 + lk * 4, q = cbS * 16 + lrow;
#pragma unroll
      for (int r = 0; r < 4; ++r) sZt[q * 256 + (p0 + r) * 4 + 2] = (f16)d[r];
    }
  }
  __syncthreads();

  // ---------------- W7: Z3 ----------------
#pragma unroll
  for (int s = 0; s < 2; ++s) {
    const int cbS = (wid & 1) * 2 + s;
    f32x4 d = mm64t(sM3, sXT, rbS, cbS, lrow, lk);
    const int p0 = rbS * 16 + lk * 4, q = cbS * 16 + lrow;
#pragma unroll
    for (int r = 0; r < 4; ++r) sZt[q * 256 + (p0 + r) * 4 + 3] = (f16)d[r];
  }
  __syncthreads();

  // ---------------- Preload (role-split registers) ----------------
  f16x8 frag[36];     // A-waves: [(k*4+nn)*2+ch] of Mk ; B-waves: [cb*9+j] of Wcat^T
  float bsrv[4];
  f16x4 iF;
#pragma unroll
  for (int e = 0; e < 4; ++e) iF[e] = (f16)((lrow == lk * 4 + e) ? 1.f : 0.f);

  if (isA) {
#pragma unroll
    for (int k = 0; k < 3; ++k)
#pragma unroll
      for (int nn = 0; nn < 4; ++nn)
#pragma unroll
        for (int ch = 0; ch < 2; ++ch)
          frag[(k * 4 + nn) * 2 + ch] =
            *(const f16x8*)((const f16*)(smem + OFF_M1 + k * 9216) + (nn * 16 + lrow) * 72 + ch * 32 + lk * 8);
  } else {
#pragma unroll
    for (int cb = 0; cb < 4; ++cb) {
#pragma unroll
      for (int j = 0; j < 9; ++j)
        frag[cb * 9 + j] = *(const f16x8*)(sWt + (cb * 16 + lrow) * 304 + j * 32 + lk * 8);
      bsrv[cb] = sBsum[cb * 16 + lrow];
    }
  }
  // zero hfrag + hTfrag (h(0) = 0): 2048 ints each
  for (int idx = tid; idx < 2048; idx += NTHREADS) {
    ((int*)(smem + OFF_HF))[idx] = 0;
    ((int*)(smem + OFF_HTF))[idx] = 0;
  }
  __syncthreads();

  // ---------------- scan: 64 steps, 2 barriers each ----------------
#pragma unroll 1
  for (int t = 0; t < NSTEPS; ++t) {
    f32x4 p0v, p1v, p2v, p3v;
    // ---- Phase A ----
    if (isA) {
      // Y_k[fb-strip] in D[f][n] orientation; store frag-linear
      const f16x8 aT0 = *(const f16x8*)(smem + OFF_HTF + (fb * 2 + 0) * 1024 + lane * 16);
      const f16x8 aT1 = *(const f16x8*)(smem + OFF_HTF + (fb * 2 + 1) * 1024 + lane * 16);
      const int lslot = (lrow + 16 * ((fb & 1) * 2 + (lk >> 1))) * 16 + (lk & 1) * 8;
#pragma unroll
      for (int k = 0; k < 3; ++k)
#pragma unroll
        for (int nn = 0; nn < 4; ++nn) {
          f32x4 d = (f32x4){0.f, 0.f, 0.f, 0.f};
          d = mfma16(aT0, frag[(k * 4 + nn) * 2 + 0], d);
          d = mfma16(aT1, frag[(k * 4 + nn) * 2 + 1], d);
          f16x4 w;
#pragma unroll
          for (int r = 0; r < 4; ++r) w[r] = (f16)d[r];
          *(f16x4*)(smem + OFF_YF + (((k * 4 + nn) * 2 + (fb >> 1)) * 1024) + lslot) = w;
        }
    } else {
      // B-wave: h*W0 + z-term (h(t), z(t) already valid)
      const f16x8 ah0 = *(const f16x8*)(smem + OFF_HF + (nb * 2 + 0) * 1024 + lane * 16);
      const f16x8 ah1 = *(const f16x8*)(smem + OFF_HF + (nb * 2 + 1) * 1024 + lane * 16);
      const f16x4 zv = *(const f16x4*)(smem + OFF_ZT + t * 512 + (nb * 16 + lrow) * 8);
      f16x8 az;
      az[0] = zv[0]; az[1] = zv[1]; az[2] = zv[2]; az[3] = zv[3];
      az[4] = (f16)0.f; az[5] = (f16)0.f; az[6] = (f16)0.f; az[7] = (f16)0.f;
      p0v = (f32x4){bsrv[0], bsrv[0], bsrv[0], bsrv[0]};
      p1v = (f32x4){bsrv[1], bsrv[1], bsrv[1], bsrv[1]};
      p2v = (f32x4){bsrv[2], bsrv[2], bsrv[2], bsrv[2]};
      p3v = (f32x4){bsrv[3], bsrv[3], bsrv[3], bsrv[3]};
      p0v = mfma16(ah0, frag[0 * 9 + 0], p0v); p0v = mfma16(ah1, frag[0 * 9 + 1], p0v); p0v = mfma16(az, frag[0 * 9 + 8], p0v);
      p1v = mfma16(ah0, frag[1 * 9 + 0], p1v); p1v = mfma16(ah1, frag[1 * 9 + 1], p1v); p1v = mfma16(az, frag[1 * 9 + 8], p1v);
      p2v = mfma16(ah0, frag[2 * 9 + 0], p2v); p2v = mfma16(ah1, frag[2 * 9 + 1], p2v); p2v = mfma16(az, frag[2 * 9 + 8], p2v);
      p3v = mfma16(ah0, frag[3 * 9 + 0], p3v); p3v = mfma16(ah1, frag[3 * 9 + 1], p3v); p3v = mfma16(az, frag[3 * 9 + 8], p3v);
    }
    __syncthreads();

    // ---- Phase B (B-waves only) ----
    if (!isA) {
#pragma unroll
      for (int k = 0; k < 3; ++k)
#pragma unroll
        for (int ch = 0; ch < 2; ++ch) {
          const f16x8 ay = *(const f16x8*)(smem + OFF_YF + (((k * 4 + nb) * 2 + ch) * 1024) + lane * 16);
          const int j = 2 + 2 * k + ch;
          p0v = mfma16(ay, frag[0 * 9 + j], p0v);
          p1v = mfma16(ay, frag[1 * 9 + j], p1v);
          p2v = mfma16(ay, frag[2 * 9 + j], p2v);
          p3v = mfma16(ay, frag[3 * 9 + j], p3v);
        }
      // sigmoid + dual-layout stores (hT direct, h row-major via K16 transpose-MFMA)
#pragma unroll
      for (int cb = 0; cb < 4; ++cb) {
        const f32x4 pv = (cb == 0) ? p0v : (cb == 1) ? p1v : (cb == 2) ? p2v : p3v;
        f16x4 hv;
#pragma unroll
        for (int r = 0; r < 4; ++r) hv[r] = (f16)(1.f / (1.f + __expf(-pv[r])));
        // hT frag-linear
        *(f16x4*)(smem + OFF_HTF + ((cb * 2 + (nb >> 1)) * 64 + lrow + 16 * ((nb & 1) * 2 + (lk >> 1))) * 16 + (lk & 1) * 8) = hv;
#if HAVE_MFMA_K16
        f32x4 d2 = mfma16k16(hv, iF, (f32x4){0.f, 0.f, 0.f, 0.f});
        f16x4 h2;
#pragma unroll
        for (int r = 0; r < 4; ++r) h2[r] = (f16)d2[r];
        // h frag-linear
        *(f16x4*)(smem + OFF_HF + ((nb * 2 + (cb >> 1)) * 64 + lrow + 16 * ((cb & 1) * 2 + (lk >> 1))) * 16 + (lk & 1) * 8) = h2;
#else
#pragma unroll
        for (int r = 0; r < 4; ++r)
          ((f16*)(smem + OFF_HF))[((nb * 2 + (cb >> 1)) * 64 + (lk * 4 + r) + 16 * ((cb & 1) * 2 + (lrow >> 3))) * 8 + (lrow & 7)] = hv[r];
#endif
      }
    }
    __syncthreads();
  }

  // ---------------- Phase 3: GCN x2 + FC + log_softmax (fp32) ----------------
  float* sLgG = (float*)(smem + OFF_ZT);              // [64][68]
  float* sT1g = (float*)(smem + OFF_WT);              // [64][68]
  float* sT2g = (float*)(smem + OFF_WT + 17408);      // [64][68]
  const f16* hF = (const f16*)(smem + OFF_HF);

  for (int idx = tid; idx < 64 * 68; idx += NTHREADS) sLgG[idx] = 0.f;
  if (tid < 64) sDeg[tid] = 0.f;
  // decode final h (frag-linear) -> fp32 row-major
  for (int idx = tid; idx < 4096; idx += NTHREADS) {
    const int n = idx >> 6, c = idx & 63;
    const f16 v = hF[(((n >> 4) * 2 + (c >> 5)) * 64 + (n & 15) + 16 * ((c >> 3) & 3)) * 8 + (c & 7)];
    sT1g[n * 68 + c] = (float)v;
  }
  if (tid < 4) sLogit[tid] = bfc[tid];
  __syncthreads();
  for (int e = tid; e < EPG; e += NTHREADS)
    atomicAdd(&sDeg[edst[ebase + e] - gbase], ew[ebase + e]);
  __syncthreads();
  if (tid < 64) sDinv[tid] = rsqrtf(sDeg[tid] + 1.f);
  __syncthreads();
  for (int e = tid; e < EPG; e += NTHREADS) {
    const int sl = esrc[ebase + e] - gbase, dl = edst[ebase + e] - gbase;
    atomicAdd(&sLgG[dl * 68 + sl], sDinv[sl] * ew[ebase + e] * sDinv[dl]);
  }
  __syncthreads();
  if (tid < 64) sLgG[tid * 68 + tid] += sDinv[tid] * sDinv[tid];
  __syncthreads();

  const bool isTile = tid < 256;
  const int i4 = ((tid >> 4) & 15) * 4;
  const int j4 = (tid & 15) * 4;

  if (isTile) {                                       // xw1 = h @ w1 -> sT2g
    float m[4][4] = {};
    mm4x4_acc<64>(m, sT1g, 68, i4, w1, 64, j4);
#pragma unroll
    for (int rr = 0; rr < 4; ++rr)
      *(float4*)(sT2g + (i4 + rr) * 68 + j4) = make_float4(m[rr][0], m[rr][1], m[rr][2], m[rr][3]);
  }
  __syncthreads();
  if (isTile) {                                       // z1 = relu(Ag @ xw1 + b1) -> sT1g
    float m[4][4] = {};
    mm4x4_acc<64>(m, sLgG, 68, i4, sT2g, 68, j4);
#pragma unroll
    for (int rr = 0; rr < 4; ++rr) {
      float4 o;
      o.x = fmaxf(m[rr][0] + b1[j4 + 0], 0.f);
      o.y = fmaxf(m[rr][1] + b1[j4 + 1], 0.f);
      o.z = fmaxf(m[rr][2] + b1[j4 + 2], 0.f);
      o.w = fmaxf(m[rr][3] + b1[j4 + 3], 0.f);
      *(float4*)(sT1g + (i4 + rr) * 68 + j4) = o;
    }
  }
  __syncthreads();
  if (isTile && j4 < 32) {                            // xw2 = z1 @ w2 -> sT2g
    float m[4][4] = {};
    mm4x4_acc<64>(m, sT1g, 68, i4, w2, 32, j4);
#pragma unroll
    for (int rr = 0; rr < 4; ++rr)
      *(float4*)(sT2g + (i4 + rr) * 68 + j4) = make_float4(m[rr][0], m[rr][1], m[rr][2], m[rr][3]);
  }
  __syncthreads();
  if (isTile && j4 < 32) {                            // z2 = relu(Ag @ xw2 + b2) -> sT1g
    float m[4][4] = {};
    mm4x4_acc<64>(m, sLgG, 68, i4, sT2g, 68, j4);
#pragma unroll
    for (int rr = 0; rr < 4; ++rr) {
      float4 o;
      o.x = fmaxf(m[rr][0] + b2[j4 + 0], 0.f);
      o.y = fmaxf(m[rr][1] + b2[j4 + 1], 0.f);
      o.z = fmaxf(m[rr][2] + b2[j4 + 2], 0.f);
      o.w = fmaxf(m[rr][3] + b2[j4 + 3], 0.f);
      *(float4*)(sT1g + (i4 + rr) * 68 + j4) = o;
    }
  }
  __syncthreads();

  // FC + log_softmax
  float q0 = 0.f, q1 = 0.f, q2 = 0.f, q3 = 0.f;
  for (int f = tid; f < 2048; f += NTHREADS) {
    const int n = f >> 5, c = f & 31;
    const float v = sT1g[n * 68 + c];
    const float4 wv = *(const float4*)(wfc + f * 4);
    q0 += v * wv.x; q1 += v * wv.y; q2 += v * wv.z; q3 += v * wv.w;
  }
#pragma unroll
  for (int off = 1; off < 64; off <<= 1) {
    q0 += __shfl_xor(q0, off);
    q1 += __shfl_xor(q1, off);
    q2 += __shfl_xor(q2, off);
    q3 += __shfl_xor(q3, off);
  }
  if ((tid & 63) == 0) {
    atomicAdd(&sLogit[0], q0);
    atomicAdd(&sLogit[1], q1);
    atomicAdd(&sLogit[2], q2);
    atomicAdd(&sLogit[3], q3);
  }
  __syncthreads();
  if (tid == 0) {
    const float l0 = sLogit[0], l1 = sLogit[1], l2 = sLogit[2], l3 = sLogit[3];
    const float mx = fmaxf(fmaxf(l0, l1), fmaxf(l2, l3));
    const float s = expf(l0 - mx) + expf(l1 - mx) + expf(l2 - mx) + expf(l3 - mx);
    const float lse = mx + logf(s);
    out[b * 4 + 0] = l0 - lse;
    out[b * 4 + 1] = l1 - lse;
    out[b * 4 + 2] = l2 - lse;
    out[b * 4 + 3] = l3 - lse;
  }
}

extern "C" void kernel_launch(void* const* d_in, const int* in_sizes, int n_in,
                              void* d_out, int out_size, void* d_ws, size_t ws_size,
                              hipStream_t stream) {
  gcrnn_mfma4<<<NBLOCKS, NTHREADS, 0, stream>>>(
      (const float*)d_in[0],   // x
      (const float*)d_in[1],   // edge_weight
      (const float*)d_in[2],   // wA
      (const float*)d_in[3],   // bA
      (const float*)d_in[4],   // wB
      (const float*)d_in[5],   // bB
      (const float*)d_in[6],   // w1
      (const float*)d_in[7],   // b1
      (const float*)d_in[8],   // w2
      (const float*)d_in[9],   // b2
      (const float*)d_in[10],  // wfc
      (const float*)d_in[11],  // bfc
      (const int*)d_in[12],    // edge_src
      (const int*)d_in[13],    // edge_dst
      (float*)d_out);
}